// Round 4
// baseline (418.137 us; speedup 1.0000x reference)
//
#include <hip/hip_runtime.h>
#include <hip/hip_bf16.h>

// CTC forward loss, fused. B=256, T=256, C=1024, L=64, S=129, blank=1023.
//
// logp[b,t,c] = log(y+EPS) - log(rowsum + C*EPS)  (log_softmax collapses).
// Only 65 classes/(b,t) used: 64 labels + blank. Logs in BASE 2 (native
// v_exp_f32/v_log_f32); final loglik scaled by ln2.
//
// Round-4 change: emit phase stages each row into a per-wave LDS slot via
// global_load_lds (async DMA, no VGPR cost -> MLP decoupled from the register
// allocator, which in rounds 2-3 serialized VGPR-staged loads: 805-1080 GB/s,
// VALUBusy 10%). Row sum + label gather then read LDS, not L1.
//
// One block (16 waves) per batch element; wave 0 then runs the 255-step
// alpha recursion from LDS. Lane j holds alpha[2j] (a0) and alpha[2j+1] (a1);
// alpha[128] (a2) replicated. skip at odd pos 2j+1 iff j>=1 && lab[j]!=lab[j-1].

#define NEGF (-1e30f)

typedef __attribute__((address_space(1))) const unsigned int GUI;
typedef __attribute__((address_space(3))) unsigned int LUI;

__device__ __forceinline__ float lse2(float a, float b) {
    float m = fmaxf(a, b);
    return m + log2f(exp2f(a - m) + exp2f(b - m));
}
__device__ __forceinline__ float lse3(float a, float b, float c) {
    float m = fmaxf(fmaxf(a, b), c);
    return m + log2f(exp2f(a - m) + exp2f(b - m) + exp2f(c - m));
}

__global__ void __launch_bounds__(1024) ctc_fused_kernel(
    const float* __restrict__ y, const int* __restrict__ lab,
    float* __restrict__ out)
{
    __shared__ float stage[16][1024];  // 64 KB: one 4 KB row slot per wave
    __shared__ float lpl_s[256][64];   // 64 KB: [t][label-pos]
    __shared__ float lpb_s[256];       // 1 KB:  [t] blank logp

    const int b    = blockIdx.x;
    const int wave = threadIdx.x >> 6;
    const int lane = threadIdx.x & 63;

    const int myLab = lab[(b << 6) + lane];   // label j = lane (L=64)

    float* slot = &stage[wave][0];

    // ---- emit phase: wave w handles rows t = 16w .. 16w+15 ----
    for (int i = 0; i < 16; ++i) {
        const int t = (wave << 4) + i;
        const float* __restrict__ yr = y + ((size_t)((b << 8) + t) << 10);

        // DMA the 4 KB row into this wave's LDS slot: 4 x (16 B/lane x 64).
        // LDS dest is wave-uniform base + lane*16 -> contiguous, matches the
        // global layout (lane-major 16 B chunks).
        #pragma unroll
        for (int q = 0; q < 4; ++q) {
            const float* g = yr + (q << 8) + (lane << 2);
            __builtin_amdgcn_global_load_lds((GUI*)g, (LUI*)(slot + (q << 8)),
                                             16, 0, 0);
        }
        __builtin_amdgcn_s_waitcnt(0);   // drain this wave's DMA (vmcnt)

        // row sum from LDS (conflict-free: lane-major 16 B strides)
        float s = 0.f;
        #pragma unroll
        for (int q = 0; q < 4; ++q) {
            float4 v = *(const float4*)(slot + (q << 8) + (lane << 2));
            s += (v.x + v.y) + (v.z + v.w);
        }
        #pragma unroll
        for (int off = 32; off; off >>= 1) s += __shfl_xor(s, off);

        const float norm = log2f(s + 1.024e-4f);   // log2(rowsum + C*EPS)
        const float yv   = slot[myLab];            // LDS gather (~2-4 way)
        lpl_s[t][lane] = log2f(yv + 1e-7f) - norm;
        if (lane == 0)
            lpb_s[t] = log2f(slot[1023] + 1e-7f) - norm;  // blank = C-1
    }
    __syncthreads();

    if (wave != 0) return;   // 15 waves retire; wave 0 runs the recursion

    const int prevLab = __shfl_up(myLab, 1);
    const bool skip   = (lane >= 1) && (myLab != prevLab);

    // t = 0: alpha0[s] = (s < 2) ? emit[0,s] : NEG
    float eb = lpb_s[0];
    float el = lpl_s[0][lane];
    float a0 = (lane == 0) ? eb : NEGF;
    float a1 = (lane == 0) ? el : NEGF;
    float a2 = NEGF;

    // prefetch t=1
    float ebp = lpb_s[1];
    float elp = lpl_s[1][lane];

    for (int t = 1; t < 256; ++t) {
        eb = ebp; el = elp;
        if (t < 255) { ebp = lpb_s[t + 1]; elp = lpl_s[t + 1][lane]; }
        float p1 = __shfl_up(a1, 1);              // alpha[2j-1]
        if (lane == 0) p1 = NEGF;
        float a1_63 = __shfl(a1, 63);             // alpha[127]
        float n0 = lse2(a0, p1) + eb;
        float n1 = lse3(a1, a0, skip ? p1 : NEGF) + el;
        float n2 = lse2(a2, a1_63) + eb;
        a0 = n0; a1 = n1; a2 = n2;
    }

    // tail = alpha[127], alpha[128]
    float t127 = __shfl(a1, 63);
    float ll = lse2(t127, a2);
    if (lane == 0)
        out[b] = -ll * 0.6931471805599453f;       // base-2 -> natural log
}

extern "C" void kernel_launch(void* const* d_in, const int* in_sizes, int n_in,
                              void* d_out, int out_size, void* d_ws, size_t ws_size,
                              hipStream_t stream) {
    const int*   y_true = (const int*)d_in[0];    // (B, L)
    const float* y_pred = (const float*)d_in[1];  // (B, T, C) float32
    float* out = (float*)d_out;                   // (B, 1) float32

    ctc_fused_kernel<<<256, 1024, 0, stream>>>(y_pred, y_true, out);
}

// Round 5
// 413.407 us; speedup vs baseline: 1.0114x; 1.0114x over previous
//
#include <hip/hip_runtime.h>
#include <hip/hip_bf16.h>

// CTC forward loss. B=256, T=256, C=1024, L=64, S=129, blank=1023.
//
// logp[b,t,c] = log(y+EPS) - log(rowsum + C*EPS)  (log_softmax collapses).
// Only 65 classes/(b,t) used: 64 labels + blank. Logs in BASE 2 (native
// v_exp_f32/v_log_f32); final loglik scaled by ln2.
//
// Round-5: back to two kernels. Rounds 2-4 fused (256 blocks x 1024 thr,
// 1 block/CU) pinned all three emit variants at ~1.7 TB/s effective ->
// dispatch-shape limit, not per-wave MLP. Emit now runs at the m13-verified
// streaming shape (4096 x 256, no LDS, 8 blocks/CU). Alpha stages its 65 KB
// emit slice into LDS via global_load_lds (round-4-validated pattern), then
// one wave runs the recursion from LDS (round-1's global-latency chain fix).

#define NEGF (-1e30f)

typedef __attribute__((address_space(1))) const unsigned int GUI;
typedef __attribute__((address_space(3))) unsigned int LUI;

__device__ __forceinline__ float lse2(float a, float b) {
    float m = fmaxf(a, b);
    return m + log2f(exp2f(a - m) + exp2f(b - m));
}
__device__ __forceinline__ float lse3(float a, float b, float c) {
    float m = fmaxf(fmaxf(a, b), c);
    return m + log2f(exp2f(a - m) + exp2f(b - m) + exp2f(c - m));
}

// 4096 blocks x 256 threads; block covers 16 consecutive rows (same b since
// 16 | 256); wave w does rows 4w..4w+3. One row per wave-iteration: 4x float4
// loads, shfl-butterfly rowsum, L1-hot gathers, coalesced 256 B lpl write.
__global__ void __launch_bounds__(256) emit_kernel(
    const float* __restrict__ y, const int* __restrict__ lab,
    float* __restrict__ lpl, float* __restrict__ lpb)
{
    const int wave = threadIdx.x >> 6;            // 0..3
    const int lane = threadIdx.x & 63;
    const int row0 = (blockIdx.x << 4) + (wave << 2);
    const int b    = row0 >> 8;                   // T = 256
    const int myLab = lab[(b << 6) + lane];

    #pragma unroll
    for (int r = 0; r < 4; ++r) {
        const int row = row0 + r;
        const float* __restrict__ yr = y + ((size_t)row << 10);
        const float4* __restrict__ yr4 = (const float4*)yr;
        float4 v0 = yr4[lane];
        float4 v1 = yr4[lane + 64];
        float4 v2 = yr4[lane + 128];
        float4 v3 = yr4[lane + 192];
        float s = (v0.x + v0.y + v0.z + v0.w) + (v1.x + v1.y + v1.z + v1.w)
                + (v2.x + v2.y + v2.z + v2.w) + (v3.x + v3.y + v3.z + v3.w);
        #pragma unroll
        for (int off = 32; off; off >>= 1) s += __shfl_xor(s, off);

        const float norm = log2f(s + 1.024e-4f);     // log2(rowsum + C*EPS)
        const float yv = yr[myLab];                   // L1-hot gather
        const float nb = yr[1023];                    // blank = C-1
        lpl[((size_t)row << 6) + lane] = log2f(yv + 1e-7f) - norm;
        if (lane == 0)
            lpb[row] = log2f(nb + 1e-7f) - norm;
    }
}

// 256 blocks x 256 threads. 4 waves DMA-stage lpl[b] (64 KB) + lpb[b] (1 KB)
// into LDS, then wave 0 runs the 255-step alpha recursion from LDS.
// Lane j holds alpha[2j] (a0) and alpha[2j+1] (a1); alpha[128] (a2)
// replicated. skip at odd pos 2j+1 iff j>=1 && lab[j]!=lab[j-1].
__global__ void __launch_bounds__(256) ctc_alpha_kernel(
    const int* __restrict__ lab,
    const float* __restrict__ lpl, const float* __restrict__ lpb,
    float* __restrict__ out)
{
    __shared__ float lpl_s[256 * 64];   // 64 KB: [t][label-pos]
    __shared__ float lpb_s[256];        // 1 KB:  [t]

    const int b    = blockIdx.x;
    const int wave = threadIdx.x >> 6;
    const int lane = threadIdx.x & 63;

    // stage: wave w copies 16 KB (16 x 1 KB DMA; LDS dest = uniform base +
    // lane*16, matching the contiguous global layout — round-4-verified).
    const float* __restrict__ gb = lpl + ((size_t)b << 14);
    #pragma unroll
    for (int c = 0; c < 16; ++c) {
        const int off = (wave << 12) + (c << 8) + (lane << 2);  // floats
        __builtin_amdgcn_global_load_lds((GUI*)(gb + off), (LUI*)(lpl_s + off),
                                         16, 0, 0);
    }
    if (wave == 0) {
        // 256 floats, 4 B/lane
        __builtin_amdgcn_global_load_lds((GUI*)(lpb + (b << 8) + lane),
                                         (LUI*)(lpb_s + lane), 4, 0, 0);
        __builtin_amdgcn_global_load_lds((GUI*)(lpb + (b << 8) + 64 + lane),
                                         (LUI*)(lpb_s + 64 + lane), 4, 0, 0);
        __builtin_amdgcn_global_load_lds((GUI*)(lpb + (b << 8) + 128 + lane),
                                         (LUI*)(lpb_s + 128 + lane), 4, 0, 0);
        __builtin_amdgcn_global_load_lds((GUI*)(lpb + (b << 8) + 192 + lane),
                                         (LUI*)(lpb_s + 192 + lane), 4, 0, 0);
    }
    __builtin_amdgcn_s_waitcnt(0);
    __syncthreads();

    if (wave != 0) return;

    const int myLab   = lab[(b << 6) + lane];
    const int prevLab = __shfl_up(myLab, 1);
    const bool skip   = (lane >= 1) && (myLab != prevLab);

    // t = 0: alpha0[s] = (s < 2) ? emit[0,s] : NEG
    float eb = lpb_s[0];
    float el = lpl_s[lane];
    float a0 = (lane == 0) ? eb : NEGF;
    float a1 = (lane == 0) ? el : NEGF;
    float a2 = NEGF;

    float ebp = lpb_s[1];
    float elp = lpl_s[64 + lane];

    for (int t = 1; t < 256; ++t) {
        eb = ebp; el = elp;
        if (t < 255) { ebp = lpb_s[t + 1]; elp = lpl_s[((t + 1) << 6) + lane]; }
        float p1 = __shfl_up(a1, 1);              // alpha[2j-1]
        if (lane == 0) p1 = NEGF;
        float sp1 = skip ? p1 : NEGF;
        float a1_63 = __shfl(a1, 63);             // alpha[127]
        float n0 = lse2(a0, p1) + eb;
        float n1 = lse3(a1, a0, sp1) + el;
        float n2 = lse2(a2, a1_63) + eb;
        a0 = n0; a1 = n1; a2 = n2;
    }

    // tail = alpha[127], alpha[128]
    float t127 = __shfl(a1, 63);
    float ll = lse2(t127, a2);
    if (lane == 0)
        out[b] = -ll * 0.6931471805599453f;       // base-2 -> natural log
}

extern "C" void kernel_launch(void* const* d_in, const int* in_sizes, int n_in,
                              void* d_out, int out_size, void* d_ws, size_t ws_size,
                              hipStream_t stream) {
    const int*   y_true = (const int*)d_in[0];    // (B, L)
    const float* y_pred = (const float*)d_in[1];  // (B, T, C) float32
    float* out = (float*)d_out;                   // (B, 1) float32

    float* lpl = (float*)d_ws;                            // B*T*64 floats
    float* lpb = lpl + (size_t)256 * 256 * 64;            // B*T floats

    emit_kernel<<<4096, 256, 0, stream>>>(y_pred, y_true, lpl, lpb);
    ctc_alpha_kernel<<<256, 256, 0, stream>>>(y_true, lpl, lpb, out);
}